// Round 11
// baseline (3367.678 us; speedup 1.0000x reference)
//
#include <hip/hip_runtime.h>
#include <hip/hip_bf16.h>

// ResNetTTT. Round 11: TTT step rewritten with the within-step dual form:
//  Z1q = xq@W1old + b1old - eta*(D1+1)@gZ1   (D1 = xq@xk^T, 4x4)
//  Z2q = X2q@W2old + b2old - eta*(G2+1)@gZ2  (G2 = X2q@X2^T, 4x4)
// => S6 merges into S1 (shared W1old frags); S7 uses OLD W2T; all weight RMWs
// overlap MFMA/LN phases; 7 barriers/step (was 8). Corrections in fp32.

#define ERF_CF 0.70710678118654752f
#define PDF_CF 0.3989422804014327f
#define ETA 0.025f   // TTT_LR / MB

typedef __attribute__((ext_vector_type(8))) short bfrag;    // 8 bf16 (4 VGPR)
typedef __attribute__((ext_vector_type(4))) float f32x4;

union FB { bfrag v; unsigned short u[8]; unsigned d[4]; };

__device__ __forceinline__ float wsum(float v) {
#pragma unroll
  for (int o = 32; o > 0; o >>= 1) v += __shfl_xor(v, o, 64);
  return v;
}

__device__ __forceinline__ unsigned pack_split(float x) {
  unsigned u = __float_as_uint(x);
  unsigned hb = u & 0xFFFF0000u;
  float lf = x - __uint_as_float(hb);
  return hb | (__float_as_uint(lf) >> 16);
}
__device__ __forceinline__ float uns(unsigned short hs, unsigned short ls) {
  return __uint_as_float((unsigned)hs << 16) + __uint_as_float((unsigned)ls << 16);
}
__device__ __forceinline__ float fb_el(const FB& H, const FB& L, int e) {
  return __uint_as_float((unsigned)H.u[e] << 16) +
         __uint_as_float((unsigned)L.u[e] << 16);
}
__device__ __forceinline__ void split2(float f, unsigned short& hs, unsigned short& ls) {
  unsigned u = __float_as_uint(f);
  unsigned hb = u & 0xFFFF0000u;
  hs = (unsigned short)(u >> 16);
  ls = (unsigned short)(__float_as_uint(f - __uint_as_float(hb)) >> 16);
}
__device__ __forceinline__ f32x4 mm3(bfrag ah, bfrag al, bfrag bh, bfrag bl, f32x4 acc) {
  acc = __builtin_amdgcn_mfma_f32_16x16x32_bf16(ah, bh, acc, 0, 0, 0);
  acc = __builtin_amdgcn_mfma_f32_16x16x32_bf16(ah, bl, acc, 0, 0, 0);
  acc = __builtin_amdgcn_mfma_f32_16x16x32_bf16(al, bh, acc, 0, 0, 0);
  return acc;
}

// ---------------------------------------------------------------------------
// prep_all: split all weights into hi/lo bf16 planes, layout [n][k].
// ---------------------------------------------------------------------------
__global__ __launch_bounds__(256) void prep_all(
    const float* __restrict__ c1w, const float* __restrict__ cw,
    const float* __restrict__ wq, const float* __restrict__ wk,
    const float* __restrict__ wv, const float* __restrict__ wo_,
    const float* __restrict__ fcw, const float* __restrict__ fc2w,
    unsigned short* __restrict__ WH, unsigned short* __restrict__ WL) {
  int id = blockIdx.x * 256 + threadIdx.x;
  float val;
  if (id < 16384) {
    val = c1w[id];
  } else if (id < 1589248) {
    int j = id - 16384;
    int cv = j / 196608;
    int r = j - cv * 196608;
    int co = r / 768;
    int k = r - co * 768;
    int tt = k >> 8, ci = k & 255;
    val = cw[((cv * 256 + co) * 256 + ci) * 3 + tt];
  } else if (id < 1851392) {
    int j = id - 1589248;
    int which = j >> 16;
    int r = j & 65535;
    int out = r >> 8, in = r & 255;
    const float* Wp = which == 0 ? wq : which == 1 ? wk : which == 2 ? wv : wo_;
    val = Wp[in * 256 + out];
  } else if (id < 1982464) {
    int j = id - 1851392;
    int out = j >> 8, in = j & 255;
    val = fcw[in * 512 + out];
  } else {
    int j = id - 1982464;
    int out = j >> 9, in = j & 511;
    val = fc2w[in * 64 + out];
  }
  unsigned short hs, ls;
  split2(val, hs, ls);
  WH[id] = hs;
  WL[id] = ls;
}

__global__ __launch_bounds__(256) void zero_halo_pl(
    unsigned short* __restrict__ cAH, unsigned short* __restrict__ cAL,
    unsigned short* __restrict__ cBH, unsigned short* __restrict__ cBL) {
  int id = blockIdx.x * 256 + threadIdx.x;  // 0..8191
  int buf = id >> 11;
  int r = id & 2047;
  int b = r >> 9, row = (r >> 8) & 1, c = r & 255;
  unsigned short* p = buf == 0 ? cAH : buf == 1 ? cAL : buf == 2 ? cBH : cBL;
  p[(b * 1026 + row * 1025) * 256 + c] = 0;
}

// ---------------------------------------------------------------------------
// Direct-from-global split-bf16 MFMA GEMM (unchanged from R10).
// ---------------------------------------------------------------------------
template <int AF32, int HALOA, int BIAS, int RELU, int EPI, int ACC>
__global__ __launch_bounds__(256) void gemm_mf(
    const unsigned short* __restrict__ AH, const unsigned short* __restrict__ AL,
    const float* __restrict__ Af32,
    const unsigned short* __restrict__ BH, const unsigned short* __restrict__ BL,
    const float* __restrict__ bias,
    const unsigned short* __restrict__ resH, const unsigned short* __restrict__ resL,
    float* __restrict__ outF, unsigned short* __restrict__ outH,
    unsigned short* __restrict__ outL, float* __restrict__ acc4,
    int N, int K) {
  const int tid = threadIdx.x;
  const int w = tid >> 6, lane = tid & 63;
  const int a = lane & 15, g = lane >> 4;
  const int s = w >> 1, ch = w & 1;
  const int bm = blockIdx.x * 32, bn = blockIdx.y * 64;
  const int rowA = bm + 16 * s + a;
  long abase;
  if constexpr (HALOA)
    abase = (long)((rowA >> 10) * 1026 + (rowA & 1023)) * 256;
  else
    abase = (long)rowA * K;
  const int cb0 = bn + (ch * 2) * 16 + a;
  const int cb1 = cb0 + 16;
  f32x4 acc0 = {0.f, 0.f, 0.f, 0.f}, acc1 = {0.f, 0.f, 0.f, 0.f};
#pragma unroll 2
  for (int kk = 0; kk < K; kk += 32) {
    FB ah, al;
    if constexpr (AF32) {
      const float* ap = Af32 + abase + kk + g * 8;
      float av[8];
      *(float4*)&av[0] = *(const float4*)ap;
      *(float4*)&av[4] = *(const float4*)(ap + 4);
#pragma unroll
      for (int e = 0; e < 8; ++e) split2(av[e], ah.u[e], al.u[e]);
    } else {
      ah.v = *(const bfrag*)&AH[abase + kk + g * 8];
      al.v = *(const bfrag*)&AL[abase + kk + g * 8];
    }
    FB b0h, b0l, b1h, b1l;
    b0h.v = *(const bfrag*)&BH[(long)cb0 * K + kk + g * 8];
    b0l.v = *(const bfrag*)&BL[(long)cb0 * K + kk + g * 8];
    b1h.v = *(const bfrag*)&BH[(long)cb1 * K + kk + g * 8];
    b1l.v = *(const bfrag*)&BL[(long)cb1 * K + kk + g * 8];
    acc0 = mm3(ah.v, al.v, b0h.v, b0l.v, acc0);
    acc1 = mm3(ah.v, al.v, b1h.v, b1l.v, acc1);
  }
#pragma unroll
  for (int i = 0; i < 2; ++i) {
    f32x4 av = i ? acc1 : acc0;
    int col = i ? cb1 : cb0;
    float bv = 0.f;
    if constexpr (BIAS) bv = bias[col];
#pragma unroll
    for (int q = 0; q < 4; ++q) {
      int r = bm + 16 * s + g * 4 + q;
      float val = av[q] + bv;
      if constexpr (RELU) val = fmaxf(val, 0.f);
      if constexpr (EPI == 4) {
        long ri = (long)r * N + col;
        val += uns(resH[ri], resL[ri]);
      }
      if constexpr (EPI == 0 || EPI == 4) {
        outF[(long)r * N + col] = val;
      } else if constexpr (EPI == 1) {
        long hi = (long)((r >> 10) * 1026 + (r & 1023) + 1) * 256 + col;
        unsigned short hs, ls;
        split2(val, hs, ls);
        outH[hi] = hs;
        outL[hi] = ls;
      } else if constexpr (EPI == 2) {
        int b_ = r >> 10, l = r & 1023, hq = col >> 6;
        long oidx = (((long)(b_ * 4 + hq) * 1024 + l) << 6) + (col & 63);
        outF[oidx] = val;
      } else if constexpr (EPI == 3) {
        long oi = (long)r * N + col;
        unsigned short hs, ls;
        split2(val, hs, ls);
        outH[oi] = hs;
        outL[oi] = ls;
      }
      if constexpr (ACC == 1) {
        acc4[(long)r * 256 + col] = val;
      } else if constexpr (ACC == 2) {
        acc4[(long)r * 256 + col] += val;
      }
    }
  }
}

// LayerNorm(256) -> hi/lo planes.
__global__ __launch_bounds__(256) void ln_pl(const float* __restrict__ in,
                                             unsigned short* __restrict__ oH,
                                             unsigned short* __restrict__ oL,
                                             const float* __restrict__ w,
                                             const float* __restrict__ bb,
                                             float eps) {
  int row = blockIdx.x * 4 + (threadIdx.x >> 6);
  int l = threadIdx.x & 63;
  float4 v = ((const float4*)(in + (long)row * 256))[l];
  float s = wsum(v.x + v.y + v.z + v.w);
  float mu = s * (1.0f / 256.0f);
  float dx = v.x - mu, dy = v.y - mu, dz = v.z - mu, dw = v.w - mu;
  float rstd = rsqrtf(wsum(dx * dx + dy * dy + dz * dz + dw * dw) * (1.0f / 256.0f) + eps);
  float4 wv = ((const float4*)w)[l];
  float4 bv = ((const float4*)bb)[l];
  float rr[4];
  rr[0] = wv.x * dx * rstd + bv.x;
  rr[1] = wv.y * dy * rstd + bv.y;
  rr[2] = wv.z * dz * rstd + bv.z;
  rr[3] = wv.w * dw * rstd + bv.w;
  long base = (long)row * 256 + l * 4;
#pragma unroll
  for (int j = 0; j < 4; ++j) {
    unsigned short hs, ls;
    split2(rr[j], hs, ls);
    oH[base + j] = hs;
    oL[base + j] = ls;
  }
}

// ---------------------------------------------------------------------------
// TTT scan, dual-form step. 512 threads (8 waves, 2/SIMD). 7 barriers/step.
// ---------------------------------------------------------------------------
__global__ __launch_bounds__(512, 2) void ttt_mfma(
    const float* __restrict__ XQ, const float* __restrict__ XK,
    const float* __restrict__ XV, const float* __restrict__ W1i,
    const float* __restrict__ B1i, const float* __restrict__ W2i,
    const float* __restrict__ B2i, const float* __restrict__ LNW,
    const float* __restrict__ LNB, unsigned short* __restrict__ outH,
    unsigned short* __restrict__ outL) {
  extern __shared__ char smem[];
  unsigned short* W2Hp  = (unsigned short*)smem;   // [256][72]
  unsigned short* W2Lp  = W2Hp + 256 * 72;
  unsigned short* W2THp = W2Lp + 256 * 72;         // [64][264]
  unsigned short* W2TLp = W2THp + 64 * 264;
  unsigned short* X2Hp  = W2TLp + 64 * 264;        // [4][272] X2 then X2q
  unsigned short* X2Lp  = X2Hp + 4 * 272;
  unsigned short* xkHp  = X2Lp + 4 * 272;          // [4][80]
  unsigned short* xkLp  = xkHp + 4 * 80;
  unsigned short* xqHp  = xkLp + 4 * 80;
  unsigned short* xqLp  = xqHp + 4 * 80;
  unsigned short* gZHp  = xqLp + 4 * 80;           // [4][80]
  unsigned short* gZLp  = gZHp + 4 * 80;
  float* X2F  = (float*)(gZLp + 4 * 80);           // [4][264] fp32 X2 (old)
  float* gZ1f = X2F + 4 * 264;                     // [4][256] Z1q' then gZ1
  float* Z2f  = gZ1f + 1024;                       // [4][64] gZ2 fp32
  float* redS = Z2f + 256;                         // [2][4][64]
  float* xvL  = redS + 512;                        // [4][64]
  float* b2L  = xvL + 256;                         // [64]
  float* lwL  = b2L + 64;
  float* lbL  = lwL + 64;
  float* G1L  = lbL + 64;                          // [16] D1 grams
  float* G2L  = G1L + 16;                          // [16] G2 grams

  const int bh = blockIdx.x, b = bh >> 2, h = bh & 3;
  const int t = threadIdx.x;           // 0..511
  const int w8 = t >> 6;
  const int lane = t & 63;
  const int a = lane & 15, g = lane >> 4;
  const bool rowv = (a < 4), g0 = (g == 0);
  const int c0 = 32 * w8 + a;
  const int c1 = 32 * w8 + 16 + a;
  const int kh = w8 & 1;
  const int jc = (w8 >> 1) * 16 + a;
  const int gp_ = 2 * w8 + (lane >> 5);  // gram pair 0..15
  const int gmq = gp_ >> 2, gmk = gp_ & 3;
  const int gr = lane & 31;

  FB zf; zf.d[0] = zf.d[1] = zf.d[2] = zf.d[3] = 0;

  FB w1h[2][2], w1l[2][2];
#pragma unroll
  for (int i = 0; i < 2; ++i) {
    int cc = 32 * w8 + i * 16 + a;
#pragma unroll
    for (int kc = 0; kc < 2; ++kc) {
#pragma unroll
      for (int e = 0; e < 8; ++e) {
        int k = kc * 32 + g * 8 + e;
        unsigned p = pack_split(W1i[(h * 64 + k) * 256 + cc]);
        w1h[i][kc].u[e] = (unsigned short)(p >> 16);
        w1l[i][kc].u[e] = (unsigned short)(p & 0xFFFFu);
      }
    }
  }
  float b1r0 = B1i[h * 256 + c0];
  float b1r1 = B1i[h * 256 + c1];

  for (int i = 0; i < 32; ++i) {
    int id = t + i * 512;
    int k = id >> 6, j = id & 63;
    unsigned p = pack_split(W2i[(h * 256 + k) * 64 + j]);
    W2Hp[k * 72 + j] = (unsigned short)(p >> 16);
    W2Lp[k * 72 + j] = (unsigned short)(p & 0xFFFFu);
    int j2 = id >> 8, k2 = id & 255;
    unsigned q = pack_split(W2i[(h * 256 + k2) * 64 + j2]);
    W2THp[j2 * 264 + k2] = (unsigned short)(q >> 16);
    W2TLp[j2 * 264 + k2] = (unsigned short)(q & 0xFFFFu);
  }
  if (t < 64) { b2L[t] = B2i[h * 64 + t]; lwL[t] = LNW[h * 64 + t]; lbL[t] = LNB[h * 64 + t]; }

  const long chain = (long)bh * 65536;
  float rk = 0.f, rv = 0.f, rq = 0.f;
  if (t >= 256) {
    int u = t - 256;
    rk = XK[chain + u]; rv = XV[chain + u]; rq = XQ[chain + u];
  }

  for (int n = 0; n < 256; ++n) {
    // ---- stage inputs (waves 4-7) ----
    if (t >= 256) {
      int u = t - 256, m = u >> 6, k = u & 63;
      unsigned short hs, ls;
      split2(rk, hs, ls); xkHp[m * 80 + k] = hs; xkLp[m * 80 + k] = ls;
      split2(rq, hs, ls); xqHp[m * 80 + k] = hs; xqLp[m * 80 + k] = ls;
      xvL[u] = rv;
    }
    __syncthreads();  // B1

    float gpA[4] = {0.f, 0.f, 0.f, 0.f}, gpB[4] = {0.f, 0.f, 0.f, 0.f};

    // ---- P1: S1 + S6' (Z1 and Z1q', both vs W1old) ----
    {
      f32x4 A0 = (f32x4){b1r0, b1r0, b1r0, b1r0};
      f32x4 A1 = (f32x4){b1r1, b1r1, b1r1, b1r1};
      f32x4 Q0 = (f32x4){b1r0, b1r0, b1r0, b1r0};
      f32x4 Q1 = (f32x4){b1r1, b1r1, b1r1, b1r1};
#pragma unroll
      for (int kc = 0; kc < 2; ++kc) {
        int base = kc * 32 + g * 8;
        FB kh_ = zf, kl_ = zf, qh_ = zf, ql_ = zf;
        if (rowv) {
          kh_.v = *(const bfrag*)&xkHp[a * 80 + base];
          kl_.v = *(const bfrag*)&xkLp[a * 80 + base];
          qh_.v = *(const bfrag*)&xqHp[a * 80 + base];
          ql_.v = *(const bfrag*)&xqLp[a * 80 + base];
        }
        A0 = mm3(kh_.v, kl_.v, w1h[0][kc].v, w1l[0][kc].v, A0);
        A1 = mm3(kh_.v, kl_.v, w1h[1][kc].v, w1l[1][kc].v, A1);
        Q0 = mm3(qh_.v, ql_.v, w1h[0][kc].v, w1l[0][kc].v, Q0);
        Q1 = mm3(qh_.v, ql_.v, w1h[1][kc].v, w1l[1][kc].v, Q1);
      }
      if (g0) {
#pragma unroll
        for (int q = 0; q < 4; ++q) {
          float z = A0[q];
          float er = erff(z * ERF_CF);
          float hh = 0.5f * (1.0f + er);
          float x2 = z * hh;
          gpA[q] = hh + z * __expf(-0.5f * z * z) * PDF_CF;
          unsigned short hs, ls;
          split2(x2, hs, ls);
          X2Hp[q * 272 + c0] = hs; X2Lp[q * 272 + c0] = ls;
          X2F[q * 264 + c0] = x2;
          z = A1[q];
          er = erff(z * ERF_CF);
          hh = 0.5f * (1.0f + er);
          x2 = z * hh;
          gpB[q] = hh + z * __expf(-0.5f * z * z) * PDF_CF;
          split2(x2, hs, ls);
          X2Hp[q * 272 + c1] = hs; X2Lp[q * 272 + c1] = ls;
          X2F[q * 264 + c1] = x2;
          gZ1f[q * 256 + c0] = Q0[q];   // Z1q' parked in gZ1f
          gZ1f[q * 256 + c1] = Q1[q];
        }
      }
    }
    __syncthreads();  // B2

    // ---- P2: S2 partials (X2 x W2T-old) + D1 gram ----
    {
      f32x4 acc = (f32x4){0.f, 0.f, 0.f, 0.f};
#pragma unroll
      for (int k4 = 0; k4 < 4; ++k4) {
        int base = (kh * 4 + k4) * 32 + g * 8;
        FB ah = zf, al = zf, bhf, blf;
        if (rowv) {
          ah.v = *(const bfrag*)&X2Hp[a * 272 + base];
          al.v = *(const bfrag*)&X2Lp[a * 272 + base];
        }
        bhf.v = *(const bfrag*)&W2THp[jc * 264 + base];
        blf.v = *(const bfrag*)&W2TLp[jc * 264 + base];
        acc = mm3(ah.v, al.v, bhf.v, blf.v, acc);
      }
      if (g0) {
#pragma unroll
        for (int q = 0; q < 4; ++q) redS[(kh * 4 + q) * 64 + jc] = acc[q];
      }
      // D1[gmq][gmk] = xq[gmq] . xk[gmk]  (K=64)
      float s = uns(xqHp[gmq * 80 + gr], xqLp[gmq * 80 + gr]) *
                    uns(xkHp[gmk * 80 + gr], xkLp[gmk * 80 + gr]) +
                uns(xqHp[gmq * 80 + gr + 32], xqLp[gmq * 80 + gr + 32]) *
                    uns(xkHp[gmk * 80 + gr + 32], xkLp[gmk * 80 + gr + 32]);
      s += __shfl_xor(s, 16, 64);
      s += __shfl_xor(s, 8, 64);
      s += __shfl_xor(s, 4, 64);
      s += __shfl_xor(s, 2, 64);
      s += __shfl_xor(s, 1, 64);
      if (gr == 0) G1L[gp_] = s;
    }
    __syncthreads();  // B3

    // ---- P3: LN-l2-bwd (waves 0-3) + prefetch (waves 4-7) ----
    if (t < 256) {
      int m = w8, j = lane;
      float z2 = b2L[j] + redS[m * 64 + j] + redS[256 + m * 64 + j];
      float mu = wsum(z2) * (1.0f / 64.0f);
      float dv = z2 - mu;
      float var = wsum(dv * dv) * (1.0f / 64.0f);
      float stdv = sqrtf(var + 1e-6f);
      float zh = dv / stdv;
      float lw = lwL[j], lb = lbL[j];
      float xkf = uns(xkHp[m * 80 + j], xkLp[m * 80 + j]);
      float tgt = xvL[m * 64 + j] - xkf;
      float gg = lw * (lw * zh + lb - tgt);
      float gs = wsum(gg) * (1.0f / 64.0f);
      float gzs = wsum(gg * zh) * (1.0f / 64.0f);
      float gz2 = (gg - gs - zh * gzs) / stdv;
      unsigned short hs, ls;
      split2(gz2, hs, ls);
      gZHp[m * 80 + j] = hs; gZLp[m * 80 + j] = ls;
      Z2f[m * 64 + j] = gz2;
    } else if (n + 1 < 256) {
      int u = t - 256;
      long nb = chain + (long)(n + 1) * 256;
      rk = XK[nb + u]; rv = XV[nb + u]; rq = XQ[nb + u];
    }
    __syncthreads();  // B4

    // ---- P4: S3 (gZ1) + Z1q finalize (dual corr) + geluQ -> X2q planes ----
    {
      f32x4 A0 = (f32x4){0.f, 0.f, 0.f, 0.f};
      f32x4 A1 = (f32x4){0.f, 0.f, 0.f, 0.f};
#pragma unroll
      for (int kc = 0; kc < 2; ++kc) {
        int base = kc * 32 + g * 8;
        FB ah = zf, al = zf, b0h, b0l, b1h, b1l;
        if (rowv) {
          ah.v = *(const bfrag*)&gZHp[a * 80 + base];
          al.v = *(const bfrag*)&gZLp[a * 80 + base];
        }
        b0h.v = *(const bfrag*)&W2Hp[c0 * 72 + base];
        b0l.v = *(const bfrag*)&W2Lp[c0 * 72 + base];
        b1h.v = *(const bfrag*)&W2Hp[c1 * 72 + base];
        b1l.v = *(const bfrag*)&W2Lp[c1 * 72 + base];
        A0 = mm3(ah.v, al.v, b0h.v, b0l.v, A0);
        A1 = mm3(ah.v, al.v, b1h.v, b1l.v, A1);
      }
      if (g0) {
        float gzc0[4], gzc1[4], q0v[4], q1v[4];
#pragma unroll
        for (int q = 0; q < 4; ++q) {
          gzc0[q] = A0[q] * gpA[q];
          gzc1[q] = A1[q] * gpB[q];
          q0v[q] = gZ1f[q * 256 + c0];   // Z1q' (read before overwrite)
          q1v[q] = gZ1f[q * 256 + c1];
        }
#pragma unroll
        for (int q = 0; q < 4; ++q) {
          float d0 = G1L[q * 4 + 0] + 1.0f, d1 = G1L[q * 4 + 1] + 1.0f;
          float d2 = G1L[q * 4 + 2] + 1.0f, d3 = G1L[q * 4 + 3] + 1.0f;
          float corr0 = fmaf(d3, gzc0[3], fmaf(d2, gzc0[2], fmaf(d1, gzc0[1], d0 * gzc0[0])));
          float corr1 = fmaf(d3, gzc1[3], fmaf(d2, gzc1[2], fmaf(d1, gzc1[1], d0 * gzc1[0])));
          float z0 = fmaf(-ETA, corr0, q0v[q]);
          float z1 = fmaf(-ETA, corr1, q1v[q]);
          float x20 = 0.5f * z0 * (1.0f + erff(z0 * ERF_CF));
          float x21 = 0.5f * z1 * (1.0f + erff(z1 * ERF_CF));
          unsigned short hs, ls;
          split2(x20, hs, ls);
          X2Hp[q * 272 + c0] = hs; X2Lp[q * 272 + c0] = ls;
          split2(x21, hs, ls);
          X2Hp[q * 272 + c1] = hs; X2Lp[q * 272 + c1] = ls;
          gZ1f[q * 256 + c0] = gzc0[q];
          gZ1f[q * 256 + c1] = gzc1[q];
        }
      }
    }
    __syncthreads();  // B5

    // ---- P5: S7 (X2q x W2T-old) + G2 gram + W1/b1 upd + W2 RMW + b2 read ----
    float b2r = 0.f;
    {
      f32x4 acc = (f32x4){0.f, 0.f, 0.f, 0.f};
#pragma unroll
      for (int k4 = 0; k4 < 4; ++k4) {
        int base = (kh * 4 + k4) * 32 + g * 8;
        FB ah = zf, al = zf, bhf, blf;
        if (rowv) {
          ah.v = *(const bfrag*)&X2Hp[a * 272 + base];
          al.v = *(const bfrag*)&X2Lp[a * 272 + base];
        }
        bhf.v = *(const bfrag*)&W2THp[jc * 264 + base];
        blf.v = *(const bfrag*)&W2TLp[jc * 264 + base];
        acc = mm3(ah.v, al.v, bhf.v, blf.v, acc);
      }
      if (g0) {
#pragma unroll
        for (int q = 0; q < 4; ++q) redS[(kh * 4 + q) * 64 + jc] = acc[q];
      }
      // G2[gmq][gmk] = X2q[gmq] . X2old[gmk]  (K=256)
      float s = 0.f;
#pragma unroll
      for (int kk = 0; kk < 256; kk += 32)
        s = fmaf(uns(X2Hp[gmq * 272 + kk + gr], X2Lp[gmq * 272 + kk + gr]),
                 X2F[gmk * 264 + kk + gr], s);
      s += __shfl_xor(s, 16, 64);
      s += __shfl_xor(s, 8, 64);
      s += __shfl_xor(s, 4, 64);
      s += __shfl_xor(s, 2, 64);
      s += __shfl_xor(s, 1, 64);
      if (gr == 0) G2L[gp_] = s;
      // W1/b1 update (in-register)
      float gzA0 = gZ1f[c0], gzA1 = gZ1f[256 + c0], gzA2 = gZ1f[512 + c0], gzA3 = gZ1f[768 + c0];
      float gzB0 = gZ1f[c1], gzB1 = gZ1f[256 + c1], gzB2 = gZ1f[512 + c1], gzB3 = gZ1f[768 + c1];
      b1r0 = fmaf(-ETA, ((gzA0 + gzA1) + gzA2) + gzA3, b1r0);
      b1r1 = fmaf(-ETA, ((gzB0 + gzB1) + gzB2) + gzB3, b1r1);
#pragma unroll
      for (int kc = 0; kc < 2; ++kc) {
        int base = kc * 32 + g * 8;
        FB x0h, x0l, x1h, x1l, x2h, x2l, x3h, x3l;
        x0h.v = *(const bfrag*)&xkHp[base];       x0l.v = *(const bfrag*)&xkLp[base];
        x1h.v = *(const bfrag*)&xkHp[80 + base];  x1l.v = *(const bfrag*)&xkLp[80 + base];
        x2h.v = *(const bfrag*)&xkHp[160 + base]; x2l.v = *(const bfrag*)&xkLp[160 + base];
        x3h.v = *(const bfrag*)&xkHp[240 + base]; x3l.v = *(const bfrag*)&xkLp[240 + base];
#pragma unroll
        for (int e = 0; e < 8; ++e) {
          float k0 = fb_el(x0h, x0l, e), k1 = fb_el(x1h, x1l, e);
          float k2 = fb_el(x2h, x2l, e), k3 = fb_el(x3h, x3l, e);
          float uA = fmaf(k3, gzA3, fmaf(k2, gzA2, fmaf(k1, gzA1, k0 * gzA0)));
          float uB = fmaf(k3, gzB3, fmaf(k2, gzB2, fmaf(k1, gzB1, k0 * gzB0)));
          float fA = fmaf(-ETA, uA, fb_el(w1h[0][kc], w1l[0][kc], e));
          float fB = fmaf(-ETA, uB, fb_el(w1h[1][kc], w1l[1][kc], e));
          unsigned short hs, ls;
          split2(fA, hs, ls); w1h[0][kc].u[e] = hs; w1l[0][kc].u[e] = ls;
          split2(fB, hs, ls); w1h[1][kc].u[e] = hs; w1l[1][kc].u[e] = ls;
        }
      }
      // W2 (row-major) RMW
      {
        int kr = t & 255, jh = (t >> 8) * 32;
        float xk0 = X2F[kr], xk1 = X2F[264 + kr], xk2 = X2F[528 + kr], xk3 = X2F[792 + kr];
#pragma unroll
        for (int jj = 0; jj < 32; jj += 8) {
          int jb = jh + jj;
          float g0f[8], g1f[8], g2f[8], g3f[8];
          *(float4*)&g0f[0] = *(const float4*)&Z2f[jb];        *(float4*)&g0f[4] = *(const float4*)&Z2f[jb + 4];
          *(float4*)&g1f[0] = *(const float4*)&Z2f[64 + jb];   *(float4*)&g1f[4] = *(const float4*)&Z2f[64 + jb + 4];
          *(float4*)&g2f[0] = *(const float4*)&Z2f[128 + jb];  *(float4*)&g2f[4] = *(const float4*)&Z2f[128 + jb + 4];
          *(float4*)&g3f[0] = *(const float4*)&Z2f[192 + jb];  *(float4*)&g3f[4] = *(const float4*)&Z2f[192 + jb + 4];
          FB oh, ol, nh, nl;
          oh.v = *(const bfrag*)&W2Hp[kr * 72 + jb];
          ol.v = *(const bfrag*)&W2Lp[kr * 72 + jb];
#pragma unroll
          for (int e = 0; e < 8; ++e) {
            float uu = fmaf(xk3, g3f[e], fmaf(xk2, g2f[e], fmaf(xk1, g1f[e], xk0 * g0f[e])));
            float f = fmaf(-ETA, uu, fb_el(oh, ol, e));
            unsigned short hs, ls;
            split2(f, hs, ls);
            nh.u[e] = hs; nl.u[e] = ls;
          }
          *(bfrag*)&W2Hp[kr * 72 + jb] = nh.v;
          *(bfrag*)&W2Lp[kr * 72 + jb] = nl.v;
        }
      }
      if (t < 256) b2r = b2L[lane];
    }
    __syncthreads();  // B6

    // ---- P6: LN fwd + dual corr + output  |  W2T RMW (all)  |  b2 upd ----
    {
      if (t < 256) {
        int m = w8, j = lane;
        float z = b2r + redS[m * 64 + j] + redS[256 + m * 64 + j];
        float corr = fmaf(G2L[m * 4 + 0] + 1.f, Z2f[j],
                     fmaf(G2L[m * 4 + 1] + 1.f, Z2f[64 + j],
                     fmaf(G2L[m * 4 + 2] + 1.f, Z2f[128 + j],
                          (G2L[m * 4 + 3] + 1.f) * Z2f[192 + j])));
        z = fmaf(-ETA, corr, z);
        float mu = wsum(z) * (1.0f / 64.0f);
        float dv = z - mu;
        float var = wsum(dv * dv) * (1.0f / 64.0f);
        float rstd = rsqrtf(var + 1e-6f);
        float xqf = uns(xqHp[m * 80 + j], xqLp[m * 80 + j]);
        float val = lwL[j] * dv * rstd + lbL[j] + xqf;
        long oidx = ((long)(b * 1024 + n * 4 + m)) * 256 + h * 64 + j;
        unsigned short hs, ls;
        split2(val, hs, ls);
        outH[oidx] = hs;
        outL[oidx] = ls;
      }
      if (t < 64)
        b2L[t] -= ETA * (((Z2f[t] + Z2f[64 + t]) + Z2f[128 + t]) + Z2f[192 + t]);
      // W2T RMW (row jr, 32 k's per thread)
      {
        int jr = t & 63, kb = (t >> 6) * 32;
        float gz0 = Z2f[jr], gz1 = Z2f[64 + jr], gz2 = Z2f[128 + jr], gz3 = Z2f[192 + jr];
#pragma unroll
        for (int kk = 0; kk < 32; kk += 8) {
          int kb8 = kb + kk;
          float x0[8], x1[8], x2[8], x3[8];
          *(float4*)&x0[0] = *(const float4*)&X2F[kb8];        *(float4*)&x0[4] = *(const float4*)&X2F[kb8 + 4];
          *(float4*)&x1[0] = *(const float4*)&X2F[264 + kb8];  *(float4*)&x1[4] = *(const float4*)&X2F[264 + kb8 + 4];
          *(float4*)&x2[0] = *(const float4*)&X2F[528 + kb8];  *(float4*)&x2[4] = *(const float4*)&X2F[528 + kb8 + 4];
          *(float4*)&x3[0] = *(const float4*)&X2F[792 + kb8];  *(float4*)&x3[4] = *(const float4*)&X2F[792 + kb8 + 4];
          FB oh, ol, nh, nl;
          oh.v = *(const bfrag*)&W2THp[jr * 264 + kb8];
          ol.v = *(const bfrag*)&W2TLp[jr * 264 + kb8];
#pragma unroll
          for (int e = 0; e < 8; ++e) {
            float uu = fmaf(x3[e], gz3, fmaf(x2[e], gz2, fmaf(x1[e], gz1, x0[e] * gz0)));
            float f = fmaf(-ETA, uu, fb_el(oh, ol, e));
            unsigned short hs, ls;
            split2(f, hs, ls);
            nh.u[e] = hs; nl.u[e] = ls;
          }
          *(bfrag*)&W2THp[jr * 264 + kb8] = nh.v;
          *(bfrag*)&W2TLp[jr * 264 + kb8] = nl.v;
        }
      }
    }
    __syncthreads();  // B7
  }
}

// final (4096,64) @ (64,1) + b
__global__ __launch_bounds__(256) void fc3_kernel(const float* __restrict__ f2,
                                                  const float* __restrict__ w,
                                                  const float* __restrict__ bias,
                                                  float* __restrict__ o) {
  int m = blockIdx.x * 4 + (threadIdx.x >> 6);
  int lane = threadIdx.x & 63;
  float v = f2[m * 64 + lane] * w[lane];
  v = wsum(v);
  if (lane == 0) o[m] = v + bias[0];
}

// ---------------------------------------------------------------------------
extern "C" void kernel_launch(void* const* d_in, const int* in_sizes, int n_in,
                              void* d_out, int out_size, void* d_ws, size_t ws_size,
                              hipStream_t stream) {
  const float* x       = (const float*)d_in[0];
  const float* conv1_w = (const float*)d_in[1];
  const float* conv1_b = (const float*)d_in[2];
  const float* convs_w = (const float*)d_in[3];
  const float* convs_b = (const float*)d_in[4];
  const float* ln_w    = (const float*)d_in[5];
  const float* ln_b    = (const float*)d_in[6];
  const float* wq      = (const float*)d_in[7];
  const float* wk      = (const float*)d_in[8];
  const float* wv      = (const float*)d_in[9];
  const float* wo      = (const float*)d_in[10];
  const float* ttt_W1  = (const float*)d_in[11];
  const float* ttt_b1  = (const float*)d_in[12];
  const float* ttt_W2  = (const float*)d_in[13];
  const float* ttt_b2  = (const float*)d_in[14];
  const float* ttt_lnw = (const float*)d_in[15];
  const float* ttt_lnb = (const float*)d_in[16];
  const float* fc_w    = (const float*)d_in[17];
  const float* fc_b    = (const float*)d_in[18];
  const float* fc2_w   = (const float*)d_in[19];
  const float* fc2_b   = (const float*)d_in[20];
  const float* fc3_w   = (const float*)d_in[21];
  const float* fc3_b   = (const float*)d_in[22];

  unsigned short* U = (unsigned short*)d_ws;
  unsigned short* WH   = U;
  unsigned short* WL   = U + 2015232;
  unsigned short* cAH  = U + 4030464;
  unsigned short* cAL  = U + 5081088;
  unsigned short* cBH  = U + 6131712;
  unsigned short* cBL  = U + 7182336;
  unsigned short* tlnH = U + 8232960;
  unsigned short* tlnL = U + 9281536;
  unsigned short* toH  = U + 10330112;
  unsigned short* toL  = U + 11378688;
  float* F = (float*)d_ws;
  float* sum4 = F + 6213632;
  float* XQ   = sum4;
  float* tfull = sum4;
  float* XK   = F + 7262208;
  float* XV   = F + 8310784;
  unsigned short* f1H = (unsigned short*)XK;
  unsigned short* f1L = (unsigned short*)XV;
  float* f2 = (float*)toH;
  unsigned short* h2H = cAH;
  unsigned short* h2L = cAL;

  const int W_WT1 = 0, W_WT = 16384, W_QKVO = 1589248, W_FC = 1851392, W_FC2 = 1982464;

  dim3 blk(256);

  zero_halo_pl<<<32, blk, 0, stream>>>(cAH, cAL, cBH, cBL);
  prep_all<<<7872, blk, 0, stream>>>(conv1_w, convs_w, wq, wk, wv, wo, fc_w,
                                     fc2_w, WH, WL);

  gemm_mf<1, 0, 1, 1, 1, 0><<<dim3(128, 4), blk, 0, stream>>>(
      nullptr, nullptr, x, WH + W_WT1, WL + W_WT1, conv1_b, nullptr, nullptr,
      nullptr, cAH, cAL, nullptr, 256, 64);

  for (int i = 0; i < 8; ++i) {
    const unsigned short* iH = (i % 2 == 0) ? cAH : cBH;
    const unsigned short* iL = (i % 2 == 0) ? cAL : cBL;
    unsigned short* oH = (i % 2 == 0) ? cBH : cAH;
    unsigned short* oL = (i % 2 == 0) ? cBL : cAL;
    const unsigned short* bH = WH + W_WT + i * 196608;
    const unsigned short* bL = WL + W_WT + i * 196608;
    const float* bp = convs_b + i * 256;
    if (i == 1)
      gemm_mf<0, 1, 1, 1, 1, 1><<<dim3(128, 4), blk, 0, stream>>>(
          iH, iL, nullptr, bH, bL, bp, nullptr, nullptr, nullptr, oH, oL, sum4,
          256, 768);
    else if (i == 3 || i == 5 || i == 7)
      gemm_mf<0, 1, 1, 1, 1, 2><<<dim3(128, 4), blk, 0, stream>>>(
          iH, iL, nullptr, bH, bL, bp, nullptr, nullptr, nullptr, oH, oL, sum4,
          256, 768);
    else
      gemm_mf<0, 1, 1, 1, 1, 0><<<dim3(128, 4), blk, 0, stream>>>(
          iH, iL, nullptr, bH, bL, bp, nullptr, nullptr, nullptr, oH, oL,
          nullptr, 256, 768);
  }

  ln_pl<<<1024, blk, 0, stream>>>(sum4, tlnH, tlnL, ln_w, ln_b, 1e-5f);

  gemm_mf<0, 0, 0, 0, 2, 0><<<dim3(128, 4), blk, 0, stream>>>(
      tlnH, tlnL, nullptr, WH + W_QKVO + 0 * 65536, WL + W_QKVO + 0 * 65536,
      nullptr, nullptr, nullptr, XQ, nullptr, nullptr, nullptr, 256, 256);
  gemm_mf<0, 0, 0, 0, 2, 0><<<dim3(128, 4), blk, 0, stream>>>(
      tlnH, tlnL, nullptr, WH + W_QKVO + 1 * 65536, WL + W_QKVO + 1 * 65536,
      nullptr, nullptr, nullptr, XK, nullptr, nullptr, nullptr, 256, 256);
  gemm_mf<0, 0, 0, 0, 2, 0><<<dim3(128, 4), blk, 0, stream>>>(
      tlnH, tlnL, nullptr, WH + W_QKVO + 2 * 65536, WL + W_QKVO + 2 * 65536,
      nullptr, nullptr, nullptr, XV, nullptr, nullptr, nullptr, 256, 256);

  // TTT scan: 16 chains, 512 threads, 162816 B dynamic LDS
  const int TTT_LDS = 162816;
  (void)hipFuncSetAttribute((const void*)ttt_mfma,
                            hipFuncAttributeMaxDynamicSharedMemorySize, TTT_LDS);
  ttt_mfma<<<16, dim3(512), TTT_LDS, stream>>>(XQ, XK, XV, ttt_W1, ttt_b1,
                                               ttt_W2, ttt_b2, ttt_lnw, ttt_lnb,
                                               toH, toL);

  gemm_mf<0, 0, 0, 0, 4, 0><<<dim3(128, 4), blk, 0, stream>>>(
      toH, toL, nullptr, WH + W_QKVO + 3 * 65536, WL + W_QKVO + 3 * 65536,
      nullptr, tlnH, tlnL, tfull, nullptr, nullptr, nullptr, 256, 256);

  ln_pl<<<1024, blk, 0, stream>>>(tfull, h2H, h2L, ln_w, ln_b, 1e-5f);

  gemm_mf<0, 0, 1, 0, 3, 0><<<dim3(128, 8), blk, 0, stream>>>(
      h2H, h2L, nullptr, WH + W_FC, WL + W_FC, fc_b, nullptr, nullptr, nullptr,
      f1H, f1L, nullptr, 512, 256);
  gemm_mf<0, 0, 1, 0, 0, 0><<<dim3(128, 1), blk, 0, stream>>>(
      f1H, f1L, nullptr, WH + W_FC2, WL + W_FC2, fc2_b, nullptr, nullptr, f2,
      nullptr, nullptr, nullptr, 64, 512);
  fc3_kernel<<<1024, blk, 0, stream>>>(f2, fc3_w, fc3_b, (float*)d_out);
}

// Round 12
// 2875.660 us; speedup vs baseline: 1.1711x; 1.1711x over previous
//
#include <hip/hip_runtime.h>
#include <hip/hip_bf16.h>

// ResNetTTT. Round 12: R10 base (verified 2.93ms) + two scheduling changes in
// ttt_mfma only: (1) input staging moved from loop-top into the LN-fwd phase
// (waves 4-7 were idle there) -> 7 barriers/step, xq double-buffered;
// (2) s_setprio(1) around MFMA clusters (T5).

#define ERF_CF 0.70710678118654752f
#define PDF_CF 0.3989422804014327f
#define ETA 0.025f   // TTT_LR / MB

typedef __attribute__((ext_vector_type(8))) short bfrag;    // 8 bf16 (4 VGPR)
typedef __attribute__((ext_vector_type(4))) float f32x4;

union FB { bfrag v; unsigned short u[8]; unsigned d[4]; };

__device__ __forceinline__ float wsum(float v) {
#pragma unroll
  for (int o = 32; o > 0; o >>= 1) v += __shfl_xor(v, o, 64);
  return v;
}

__device__ __forceinline__ unsigned pack_split(float x) {
  unsigned u = __float_as_uint(x);
  unsigned hb = u & 0xFFFF0000u;
  float lf = x - __uint_as_float(hb);
  return hb | (__float_as_uint(lf) >> 16);
}
__device__ __forceinline__ float uns(unsigned short hs, unsigned short ls) {
  return __uint_as_float((unsigned)hs << 16) + __uint_as_float((unsigned)ls << 16);
}
__device__ __forceinline__ float fb_el(const FB& H, const FB& L, int e) {
  return __uint_as_float((unsigned)H.u[e] << 16) +
         __uint_as_float((unsigned)L.u[e] << 16);
}
__device__ __forceinline__ void split2(float f, unsigned short& hs, unsigned short& ls) {
  unsigned u = __float_as_uint(f);
  unsigned hb = u & 0xFFFF0000u;
  hs = (unsigned short)(u >> 16);
  ls = (unsigned short)(__float_as_uint(f - __uint_as_float(hb)) >> 16);
}
__device__ __forceinline__ f32x4 mm3(bfrag ah, bfrag al, bfrag bh, bfrag bl, f32x4 acc) {
  acc = __builtin_amdgcn_mfma_f32_16x16x32_bf16(ah, bh, acc, 0, 0, 0);
  acc = __builtin_amdgcn_mfma_f32_16x16x32_bf16(ah, bl, acc, 0, 0, 0);
  acc = __builtin_amdgcn_mfma_f32_16x16x32_bf16(al, bh, acc, 0, 0, 0);
  return acc;
}

// ---------------------------------------------------------------------------
// prep_all: split all weights into hi/lo bf16 planes, layout [n][k].
// ---------------------------------------------------------------------------
__global__ __launch_bounds__(256) void prep_all(
    const float* __restrict__ c1w, const float* __restrict__ cw,
    const float* __restrict__ wq, const float* __restrict__ wk,
    const float* __restrict__ wv, const float* __restrict__ wo_,
    const float* __restrict__ fcw, const float* __restrict__ fc2w,
    unsigned short* __restrict__ WH, unsigned short* __restrict__ WL) {
  int id = blockIdx.x * 256 + threadIdx.x;
  float val;
  if (id < 16384) {
    val = c1w[id];
  } else if (id < 1589248) {
    int j = id - 16384;
    int cv = j / 196608;
    int r = j - cv * 196608;
    int co = r / 768;
    int k = r - co * 768;
    int tt = k >> 8, ci = k & 255;
    val = cw[((cv * 256 + co) * 256 + ci) * 3 + tt];
  } else if (id < 1851392) {
    int j = id - 1589248;
    int which = j >> 16;
    int r = j & 65535;
    int out = r >> 8, in = r & 255;
    const float* Wp = which == 0 ? wq : which == 1 ? wk : which == 2 ? wv : wo_;
    val = Wp[in * 256 + out];
  } else if (id < 1982464) {
    int j = id - 1851392;
    int out = j >> 8, in = j & 255;
    val = fcw[in * 512 + out];
  } else {
    int j = id - 1982464;
    int out = j >> 9, in = j & 511;
    val = fc2w[in * 64 + out];
  }
  unsigned short hs, ls;
  split2(val, hs, ls);
  WH[id] = hs;
  WL[id] = ls;
}

__global__ __launch_bounds__(256) void zero_halo_pl(
    unsigned short* __restrict__ cAH, unsigned short* __restrict__ cAL,
    unsigned short* __restrict__ cBH, unsigned short* __restrict__ cBL) {
  int id = blockIdx.x * 256 + threadIdx.x;  // 0..8191
  int buf = id >> 11;
  int r = id & 2047;
  int b = r >> 9, row = (r >> 8) & 1, c = r & 255;
  unsigned short* p = buf == 0 ? cAH : buf == 1 ? cAL : buf == 2 ? cBH : cBL;
  p[(b * 1026 + row * 1025) * 256 + c] = 0;
}

// ---------------------------------------------------------------------------
// Direct-from-global split-bf16 MFMA GEMM (unchanged from R10).
// ---------------------------------------------------------------------------
template <int AF32, int HALOA, int BIAS, int RELU, int EPI, int ACC>
__global__ __launch_bounds__(256) void gemm_mf(
    const unsigned short* __restrict__ AH, const unsigned short* __restrict__ AL,
    const float* __restrict__ Af32,
    const unsigned short* __restrict__ BH, const unsigned short* __restrict__ BL,
    const float* __restrict__ bias,
    const unsigned short* __restrict__ resH, const unsigned short* __restrict__ resL,
    float* __restrict__ outF, unsigned short* __restrict__ outH,
    unsigned short* __restrict__ outL, float* __restrict__ acc4,
    int N, int K) {
  const int tid = threadIdx.x;
  const int w = tid >> 6, lane = tid & 63;
  const int a = lane & 15, g = lane >> 4;
  const int s = w >> 1, ch = w & 1;
  const int bm = blockIdx.x * 32, bn = blockIdx.y * 64;
  const int rowA = bm + 16 * s + a;
  long abase;
  if constexpr (HALOA)
    abase = (long)((rowA >> 10) * 1026 + (rowA & 1023)) * 256;
  else
    abase = (long)rowA * K;
  const int cb0 = bn + (ch * 2) * 16 + a;
  const int cb1 = cb0 + 16;
  f32x4 acc0 = {0.f, 0.f, 0.f, 0.f}, acc1 = {0.f, 0.f, 0.f, 0.f};
#pragma unroll 2
  for (int kk = 0; kk < K; kk += 32) {
    FB ah, al;
    if constexpr (AF32) {
      const float* ap = Af32 + abase + kk + g * 8;
      float av[8];
      *(float4*)&av[0] = *(const float4*)ap;
      *(float4*)&av[4] = *(const float4*)(ap + 4);
#pragma unroll
      for (int e = 0; e < 8; ++e) split2(av[e], ah.u[e], al.u[e]);
    } else {
      ah.v = *(const bfrag*)&AH[abase + kk + g * 8];
      al.v = *(const bfrag*)&AL[abase + kk + g * 8];
    }
    FB b0h, b0l, b1h, b1l;
    b0h.v = *(const bfrag*)&BH[(long)cb0 * K + kk + g * 8];
    b0l.v = *(const bfrag*)&BL[(long)cb0 * K + kk + g * 8];
    b1h.v = *(const bfrag*)&BH[(long)cb1 * K + kk + g * 8];
    b1l.v = *(const bfrag*)&BL[(long)cb1 * K + kk + g * 8];
    acc0 = mm3(ah.v, al.v, b0h.v, b0l.v, acc0);
    acc1 = mm3(ah.v, al.v, b1h.v, b1l.v, acc1);
  }
#pragma unroll
  for (int i = 0; i < 2; ++i) {
    f32x4 av = i ? acc1 : acc0;
    int col = i ? cb1 : cb0;
    float bv = 0.f;
    if constexpr (BIAS) bv = bias[col];
#pragma unroll
    for (int q = 0; q < 4; ++q) {
      int r = bm + 16 * s + g * 4 + q;
      float val = av[q] + bv;
      if constexpr (RELU) val = fmaxf(val, 0.f);
      if constexpr (EPI == 4) {
        long ri = (long)r * N + col;
        val += uns(resH[ri], resL[ri]);
      }
      if constexpr (EPI == 0 || EPI == 4) {
        outF[(long)r * N + col] = val;
      } else if constexpr (EPI == 1) {
        long hi = (long)((r >> 10) * 1026 + (r & 1023) + 1) * 256 + col;
        unsigned short hs, ls;
        split2(val, hs, ls);
        outH[hi] = hs;
        outL[hi] = ls;
      } else if constexpr (EPI == 2) {
        int b_ = r >> 10, l = r & 1023, hq = col >> 6;
        long oidx = (((long)(b_ * 4 + hq) * 1024 + l) << 6) + (col & 63);
        outF[oidx] = val;
      } else if constexpr (EPI == 3) {
        long oi = (long)r * N + col;
        unsigned short hs, ls;
        split2(val, hs, ls);
        outH[oi] = hs;
        outL[oi] = ls;
      }
      if constexpr (ACC == 1) {
        acc4[(long)r * 256 + col] = val;
      } else if constexpr (ACC == 2) {
        acc4[(long)r * 256 + col] += val;
      }
    }
  }
}

// LayerNorm(256) -> hi/lo planes.
__global__ __launch_bounds__(256) void ln_pl(const float* __restrict__ in,
                                             unsigned short* __restrict__ oH,
                                             unsigned short* __restrict__ oL,
                                             const float* __restrict__ w,
                                             const float* __restrict__ bb,
                                             float eps) {
  int row = blockIdx.x * 4 + (threadIdx.x >> 6);
  int l = threadIdx.x & 63;
  float4 v = ((const float4*)(in + (long)row * 256))[l];
  float s = wsum(v.x + v.y + v.z + v.w);
  float mu = s * (1.0f / 256.0f);
  float dx = v.x - mu, dy = v.y - mu, dz = v.z - mu, dw = v.w - mu;
  float rstd = rsqrtf(wsum(dx * dx + dy * dy + dz * dz + dw * dw) * (1.0f / 256.0f) + eps);
  float4 wv = ((const float4*)w)[l];
  float4 bv = ((const float4*)bb)[l];
  float rr[4];
  rr[0] = wv.x * dx * rstd + bv.x;
  rr[1] = wv.y * dy * rstd + bv.y;
  rr[2] = wv.z * dz * rstd + bv.z;
  rr[3] = wv.w * dw * rstd + bv.w;
  long base = (long)row * 256 + l * 4;
#pragma unroll
  for (int j = 0; j < 4; ++j) {
    unsigned short hs, ls;
    split2(rr[j], hs, ls);
    oH[base + j] = hs;
    oL[base + j] = ls;
  }
}

// ---------------------------------------------------------------------------
// TTT scan via MFMA. 512 threads (8 waves, 2/SIMD). 7 barriers/step.
// Staging of step n+1 inputs runs in the LN-fwd phase (waves 4-7 idle there);
// xq planes double-buffered (read by LN-fwd in the same phase).
// ---------------------------------------------------------------------------
__global__ __launch_bounds__(512, 2) void ttt_mfma(
    const float* __restrict__ XQ, const float* __restrict__ XK,
    const float* __restrict__ XV, const float* __restrict__ W1i,
    const float* __restrict__ B1i, const float* __restrict__ W2i,
    const float* __restrict__ B2i, const float* __restrict__ LNW,
    const float* __restrict__ LNB, unsigned short* __restrict__ outH,
    unsigned short* __restrict__ outL) {
  extern __shared__ char smem[];
  unsigned short* W2Hp  = (unsigned short*)smem;   // [256][72]
  unsigned short* W2Lp  = W2Hp + 256 * 72;
  unsigned short* W2THp = W2Lp + 256 * 72;         // [64][264]
  unsigned short* W2TLp = W2THp + 64 * 264;
  unsigned short* X2Hp  = W2TLp + 64 * 264;        // [4][272]
  unsigned short* X2Lp  = X2Hp + 4 * 272;
  unsigned short* xkHp  = X2Lp + 4 * 272;          // [4][72]
  unsigned short* xkLp  = xkHp + 4 * 72;
  unsigned short* xqHp  = xkLp + 4 * 72;           // [2][4][72] double-buffered
  unsigned short* xqLp  = xqHp + 2 * 4 * 72;
  unsigned short* gZHp  = xqLp + 2 * 4 * 72;       // [4][72]
  unsigned short* gZLp  = gZHp + 4 * 72;
  float* X2F  = (float*)(gZLp + 4 * 72);           // [4][264] fp32 X2
  float* gZ1f = X2F + 4 * 264;                     // [4][256]
  float* Z2f  = gZ1f + 1024;                       // [4][64] gZ2 fp32
  float* redS = Z2f + 256;                         // [2][4][64]
  float* xvL  = redS + 512;                        // [4][64]
  float* b2L  = xvL + 256;                         // [64]
  float* lwL  = b2L + 64;
  float* lbL  = lwL + 64;

  const int bh = blockIdx.x, b = bh >> 2, h = bh & 3;
  const int t = threadIdx.x;           // 0..511
  const int w8 = t >> 6;
  const int lane = t & 63;
  const int a = lane & 15, g = lane >> 4;
  const bool rowv = (a < 4), g0 = (g == 0);
  const int c0 = 32 * w8 + a;
  const int c1 = 32 * w8 + 16 + a;
  const int kh = w8 & 1;
  const int jc = (w8 >> 1) * 16 + a;

  FB zf; zf.d[0] = zf.d[1] = zf.d[2] = zf.d[3] = 0;

  FB w1h[2][2], w1l[2][2];
#pragma unroll
  for (int i = 0; i < 2; ++i) {
    int cc = 32 * w8 + i * 16 + a;
#pragma unroll
    for (int kc = 0; kc < 2; ++kc) {
#pragma unroll
      for (int e = 0; e < 8; ++e) {
        int k = kc * 32 + g * 8 + e;
        unsigned p = pack_split(W1i[(h * 64 + k) * 256 + cc]);
        w1h[i][kc].u[e] = (unsigned short)(p >> 16);
        w1l[i][kc].u[e] = (unsigned short)(p & 0xFFFFu);
      }
    }
  }
  float b1r0 = B1i[h * 256 + c0];
  float b1r1 = B1i[h * 256 + c1];

  for (int i = 0; i < 32; ++i) {
    int id = t + i * 512;
    int k = id >> 6, j = id & 63;
    unsigned p = pack_split(W2i[(h * 256 + k) * 64 + j]);
    W2Hp[k * 72 + j] = (unsigned short)(p >> 16);
    W2Lp[k * 72 + j] = (unsigned short)(p & 0xFFFFu);
    int j2 = id >> 8, k2 = id & 255;
    unsigned q = pack_split(W2i[(h * 256 + k2) * 64 + j2]);
    W2THp[j2 * 264 + k2] = (unsigned short)(q >> 16);
    W2TLp[j2 * 264 + k2] = (unsigned short)(q & 0xFFFFu);
  }
  if (t < 64) { b2L[t] = B2i[h * 64 + t]; lwL[t] = LNW[h * 64 + t]; lbL[t] = LNB[h * 64 + t]; }

  const long chain = (long)bh * 65536;
  float rk = 0.f, rv = 0.f, rq = 0.f;
  if (t >= 256) {
    int u = t - 256, m = u >> 6, k = u & 63;
    rk = XK[chain + u]; rv = XV[chain + u]; rq = XQ[chain + u];
    unsigned short hs, ls;
    split2(rk, hs, ls); xkHp[m * 72 + k] = hs; xkLp[m * 72 + k] = ls;
    split2(rq, hs, ls); xqHp[m * 72 + k] = hs; xqLp[m * 72 + k] = ls;  // buf 0
    xvL[u] = rv;
  }
  __syncthreads();

  for (int n = 0; n < 256; ++n) {
    const int XQO = (n & 1) * 288;       // xq plane buffer for this step
    float gpA[4] = {0.f, 0.f, 0.f, 0.f}, gpB[4] = {0.f, 0.f, 0.f, 0.f};

    // ---- P1: S1 = xk @ W1 + b1 ; in-reg gelu -> X2 planes + X2F ----
    {
      f32x4 A0 = (f32x4){b1r0, b1r0, b1r0, b1r0};
      f32x4 A1 = (f32x4){b1r1, b1r1, b1r1, b1r1};
      __builtin_amdgcn_s_setprio(1);
#pragma unroll
      for (int kc = 0; kc < 2; ++kc) {
        int base = kc * 32 + g * 8;
        FB ah = zf, al = zf;
        if (rowv) {
          ah.v = *(const bfrag*)&xkHp[a * 72 + base];
          al.v = *(const bfrag*)&xkLp[a * 72 + base];
        }
        A0 = mm3(ah.v, al.v, w1h[0][kc].v, w1l[0][kc].v, A0);
        A1 = mm3(ah.v, al.v, w1h[1][kc].v, w1l[1][kc].v, A1);
      }
      __builtin_amdgcn_s_setprio(0);
      if (g0) {
#pragma unroll
        for (int q = 0; q < 4; ++q) {
          float z = A0[q];
          float er = erff(z * ERF_CF);
          float hh = 0.5f * (1.0f + er);
          float x2 = z * hh;
          gpA[q] = hh + z * __expf(-0.5f * z * z) * PDF_CF;
          unsigned short hs, ls;
          split2(x2, hs, ls);
          X2Hp[q * 272 + c0] = hs; X2Lp[q * 272 + c0] = ls;
          X2F[q * 264 + c0] = x2;
          z = A1[q];
          er = erff(z * ERF_CF);
          hh = 0.5f * (1.0f + er);
          x2 = z * hh;
          gpB[q] = hh + z * __expf(-0.5f * z * z) * PDF_CF;
          split2(x2, hs, ls);
          X2Hp[q * 272 + c1] = hs; X2Lp[q * 272 + c1] = ls;
          X2F[q * 264 + c1] = x2;
        }
      }
    }
    __syncthreads();  // B2

    // ---- P2: S2 partials (split-K over kh) ----
    {
      f32x4 acc = (f32x4){0.f, 0.f, 0.f, 0.f};
      __builtin_amdgcn_s_setprio(1);
#pragma unroll
      for (int k4 = 0; k4 < 4; ++k4) {
        int base = (kh * 4 + k4) * 32 + g * 8;
        FB ah = zf, al = zf, bhf, blf;
        if (rowv) {
          ah.v = *(const bfrag*)&X2Hp[a * 272 + base];
          al.v = *(const bfrag*)&X2Lp[a * 272 + base];
        }
        bhf.v = *(const bfrag*)&W2THp[jc * 264 + base];
        blf.v = *(const bfrag*)&W2TLp[jc * 264 + base];
        acc = mm3(ah.v, al.v, bhf.v, blf.v, acc);
      }
      __builtin_amdgcn_s_setprio(0);
      if (g0) {
#pragma unroll
        for (int q = 0; q < 4; ++q) redS[(kh * 4 + q) * 64 + jc] = acc[q];
      }
    }
    __syncthreads();  // B3

    // ---- P3: LN-l2-bwd (waves 0-3) + global prefetch (waves 4-7) ----
    if (t < 256) {
      int m = w8, j = lane;
      float z2 = b2L[j] + redS[m * 64 + j] + redS[256 + m * 64 + j];
      float mu = wsum(z2) * (1.0f / 64.0f);
      float dv = z2 - mu;
      float var = wsum(dv * dv) * (1.0f / 64.0f);
      float stdv = sqrtf(var + 1e-6f);
      float zh = dv / stdv;
      float lw = lwL[j], lb = lbL[j];
      float xkf = uns(xkHp[m * 72 + j], xkLp[m * 72 + j]);
      float tgt = xvL[m * 64 + j] - xkf;
      float gg = lw * (lw * zh + lb - tgt);
      float gs = wsum(gg) * (1.0f / 64.0f);
      float gzs = wsum(gg * zh) * (1.0f / 64.0f);
      float gz2 = (gg - gs - zh * gzs) / stdv;
      unsigned short hs, ls;
      split2(gz2, hs, ls);
      gZHp[m * 72 + j] = hs; gZLp[m * 72 + j] = ls;
      Z2f[m * 64 + j] = gz2;
    } else if (n + 1 < 256) {
      int u = t - 256;
      long nb = chain + (long)(n + 1) * 256;
      rk = XK[nb + u]; rv = XV[nb + u]; rq = XQ[nb + u];
    }
    __syncthreads();  // B4

    // ---- P4: S3 (gZ1) overlapped with W2T RMW ----
    {
      f32x4 A0 = (f32x4){0.f, 0.f, 0.f, 0.f};
      f32x4 A1 = (f32x4){0.f, 0.f, 0.f, 0.f};
      __builtin_amdgcn_s_setprio(1);
#pragma unroll
      for (int kc = 0; kc < 2; ++kc) {
        int base = kc * 32 + g * 8;
        FB ah = zf, al = zf, b0h, b0l, b1h, b1l;
        if (rowv) {
          ah.v = *(const bfrag*)&gZHp[a * 72 + base];
          al.v = *(const bfrag*)&gZLp[a * 72 + base];
        }
        b0h.v = *(const bfrag*)&W2Hp[c0 * 72 + base];
        b0l.v = *(const bfrag*)&W2Lp[c0 * 72 + base];
        b1h.v = *(const bfrag*)&W2Hp[c1 * 72 + base];
        b1l.v = *(const bfrag*)&W2Lp[c1 * 72 + base];
        A0 = mm3(ah.v, al.v, b0h.v, b0l.v, A0);
        A1 = mm3(ah.v, al.v, b1h.v, b1l.v, A1);
      }
      __builtin_amdgcn_s_setprio(0);
      if (g0) {
#pragma unroll
        for (int q = 0; q < 4; ++q) {
          gZ1f[q * 256 + c0] = A0[q] * gpA[q];
          gZ1f[q * 256 + c1] = A1[q] * gpB[q];
        }
      }
      {
        int jr = t & 63, kb = (t >> 6) * 32;
        float gz0 = Z2f[jr], gz1 = Z2f[64 + jr], gz2 = Z2f[128 + jr], gz3 = Z2f[192 + jr];
#pragma unroll
        for (int kk = 0; kk < 32; kk += 8) {
          int kb8 = kb + kk;
          float x0[8], x1[8], x2[8], x3[8];
          *(float4*)&x0[0] = *(const float4*)&X2F[kb8];        *(float4*)&x0[4] = *(const float4*)&X2F[kb8 + 4];
          *(float4*)&x1[0] = *(const float4*)&X2F[264 + kb8];  *(float4*)&x1[4] = *(const float4*)&X2F[264 + kb8 + 4];
          *(float4*)&x2[0] = *(const float4*)&X2F[528 + kb8];  *(float4*)&x2[4] = *(const float4*)&X2F[528 + kb8 + 4];
          *(float4*)&x3[0] = *(const float4*)&X2F[792 + kb8];  *(float4*)&x3[4] = *(const float4*)&X2F[792 + kb8 + 4];
          FB oh, ol, nh, nl;
          oh.v = *(const bfrag*)&W2THp[jr * 264 + kb8];
          ol.v = *(const bfrag*)&W2TLp[jr * 264 + kb8];
#pragma unroll
          for (int e = 0; e < 8; ++e) {
            float uu = fmaf(x3[e], gz3, fmaf(x2[e], gz2, fmaf(x1[e], gz1, x0[e] * gz0)));
            float f = fmaf(-ETA, uu, fb_el(oh, ol, e));
            unsigned short hs, ls;
            split2(f, hs, ls);
            nh.u[e] = hs; nl.u[e] = ls;
          }
          *(bfrag*)&W2THp[jr * 264 + kb8] = nh.v;
          *(bfrag*)&W2TLp[jr * 264 + kb8] = nl.v;
        }
      }
    }
    __syncthreads();  // B5

    // ---- P5: W1/b1 reg update ; S6 ; geluB ; W2 RMW ; b2 ----
    {
      float gzA0 = gZ1f[c0], gzA1 = gZ1f[256 + c0], gzA2 = gZ1f[512 + c0], gzA3 = gZ1f[768 + c0];
      float gzB0 = gZ1f[c1], gzB1 = gZ1f[256 + c1], gzB2 = gZ1f[512 + c1], gzB3 = gZ1f[768 + c1];
      b1r0 = fmaf(-ETA, ((gzA0 + gzA1) + gzA2) + gzA3, b1r0);
      b1r1 = fmaf(-ETA, ((gzB0 + gzB1) + gzB2) + gzB3, b1r1);
#pragma unroll
      for (int kc = 0; kc < 2; ++kc) {
        int base = kc * 32 + g * 8;
        FB x0h, x0l, x1h, x1l, x2h, x2l, x3h, x3l;
        x0h.v = *(const bfrag*)&xkHp[base];       x0l.v = *(const bfrag*)&xkLp[base];
        x1h.v = *(const bfrag*)&xkHp[72 + base];  x1l.v = *(const bfrag*)&xkLp[72 + base];
        x2h.v = *(const bfrag*)&xkHp[144 + base]; x2l.v = *(const bfrag*)&xkLp[144 + base];
        x3h.v = *(const bfrag*)&xkHp[216 + base]; x3l.v = *(const bfrag*)&xkLp[216 + base];
#pragma unroll
        for (int e = 0; e < 8; ++e) {
          float k0 = fb_el(x0h, x0l, e), k1 = fb_el(x1h, x1l, e);
          float k2 = fb_el(x2h, x2l, e), k3 = fb_el(x3h, x3l, e);
          float uA = fmaf(k3, gzA3, fmaf(k2, gzA2, fmaf(k1, gzA1, k0 * gzA0)));
          float uB = fmaf(k3, gzB3, fmaf(k2, gzB2, fmaf(k1, gzB1, k0 * gzB0)));
          float fA = fmaf(-ETA, uA, fb_el(w1h[0][kc], w1l[0][kc], e));
          float fB = fmaf(-ETA, uB, fb_el(w1h[1][kc], w1l[1][kc], e));
          unsigned short hs, ls;
          split2(fA, hs, ls); w1h[0][kc].u[e] = hs; w1l[0][kc].u[e] = ls;
          split2(fB, hs, ls); w1h[1][kc].u[e] = hs; w1l[1][kc].u[e] = ls;
        }
      }
      // S6: Z1q = xq @ W1' + b1' ; in-reg gelu -> X2 planes
      {
        f32x4 A0 = (f32x4){b1r0, b1r0, b1r0, b1r0};
        f32x4 A1 = (f32x4){b1r1, b1r1, b1r1, b1r1};
        __builtin_amdgcn_s_setprio(1);
#pragma unroll
        for (int kc = 0; kc < 2; ++kc) {
          int base = kc * 32 + g * 8;
          FB ah = zf, al = zf;
          if (rowv) {
            ah.v = *(const bfrag*)&xqHp[XQO + a * 72 + base];
            al.v = *(const bfrag*)&xqLp[XQO + a * 72 + base];
          }
          A0 = mm3(ah.v, al.v, w1h[0][kc].v, w1l[0][kc].v, A0);
          A1 = mm3(ah.v, al.v, w1h[1][kc].v, w1l[1][kc].v, A1);
        }
        __builtin_amdgcn_s_setprio(0);
        if (g0) {
#pragma unroll
          for (int q = 0; q < 4; ++q) {
            float z = A0[q];
            float x2 = 0.5f * z * (1.0f + erff(z * ERF_CF));
            unsigned short hs, ls;
            split2(x2, hs, ls);
            X2Hp[q * 272 + c0] = hs; X2Lp[q * 272 + c0] = ls;
            z = A1[q];
            x2 = 0.5f * z * (1.0f + erff(z * ERF_CF));
            split2(x2, hs, ls);
            X2Hp[q * 272 + c1] = hs; X2Lp[q * 272 + c1] = ls;
          }
        }
      }
      // W2 (row-major) RMW
      {
        int kr = t & 255, jh = (t >> 8) * 32;
        float xk0 = X2F[kr], xk1 = X2F[264 + kr], xk2 = X2F[528 + kr], xk3 = X2F[792 + kr];
#pragma unroll
        for (int jj = 0; jj < 32; jj += 8) {
          int jb = jh + jj;
          float g0f[8], g1f[8], g2f[8], g3f[8];
          *(float4*)&g0f[0] = *(const float4*)&Z2f[jb];        *(float4*)&g0f[4] = *(const float4*)&Z2f[jb + 4];
          *(float4*)&g1f[0] = *(const float4*)&Z2f[64 + jb];   *(float4*)&g1f[4] = *(const float4*)&Z2f[64 + jb + 4];
          *(float4*)&g2f[0] = *(const float4*)&Z2f[128 + jb];  *(float4*)&g2f[4] = *(const float4*)&Z2f[128 + jb + 4];
          *(float4*)&g3f[0] = *(const float4*)&Z2f[192 + jb];  *(float4*)&g3f[4] = *(const float4*)&Z2f[192 + jb + 4];
          FB oh, ol, nh, nl;
          oh.v = *(const bfrag*)&W2Hp[kr * 72 + jb];
          ol.v = *(const bfrag*)&W2Lp[kr * 72 + jb];
#pragma unroll
          for (int e = 0; e < 8; ++e) {
            float uu = fmaf(xk3, g3f[e], fmaf(xk2, g2f[e], fmaf(xk1, g1f[e], xk0 * g0f[e])));
            float f = fmaf(-ETA, uu, fb_el(oh, ol, e));
            unsigned short hs, ls;
            split2(f, hs, ls);
            nh.u[e] = hs; nl.u[e] = ls;
          }
          *(bfrag*)&W2Hp[kr * 72 + jb] = nh.v;
          *(bfrag*)&W2Lp[kr * 72 + jb] = nl.v;
        }
      }
      if (t < 64)
        b2L[t] -= ETA * (((Z2f[t] + Z2f[64 + t]) + Z2f[128 + t]) + Z2f[192 + t]);
    }
    __syncthreads();  // B6

    // ---- P6: S7 (X2q x W2T-new) ----
    {
      f32x4 acc = (f32x4){0.f, 0.f, 0.f, 0.f};
      __builtin_amdgcn_s_setprio(1);
#pragma unroll
      for (int k4 = 0; k4 < 4; ++k4) {
        int base = (kh * 4 + k4) * 32 + g * 8;
        FB ah = zf, al = zf, bhf, blf;
        if (rowv) {
          ah.v = *(const bfrag*)&X2Hp[a * 272 + base];
          al.v = *(const bfrag*)&X2Lp[a * 272 + base];
        }
        bhf.v = *(const bfrag*)&W2THp[jc * 264 + base];
        blf.v = *(const bfrag*)&W2TLp[jc * 264 + base];
        acc = mm3(ah.v, al.v, bhf.v, blf.v, acc);
      }
      __builtin_amdgcn_s_setprio(0);
      if (g0) {
#pragma unroll
        for (int q = 0; q < 4; ++q) redS[(kh * 4 + q) * 64 + jc] = acc[q];
      }
    }
    __syncthreads();  // B7

    // ---- P7: LN fwd + output (waves 0-3)  |  stage step n+1 (waves 4-7) ----
    if (t < 256) {
      int m = w8, j = lane;
      float z = b2L[j] + redS[m * 64 + j] + redS[256 + m * 64 + j];
      float mu = wsum(z) * (1.0f / 64.0f);
      float dv = z - mu;
      float var = wsum(dv * dv) * (1.0f / 64.0f);
      float rstd = rsqrtf(var + 1e-6f);
      float xqf = uns(xqHp[XQO + m * 72 + j], xqLp[XQO + m * 72 + j]);
      float val = lwL[j] * dv * rstd + lbL[j] + xqf;
      long oidx = ((long)(b * 1024 + n * 4 + m)) * 256 + h * 64 + j;
      unsigned short hs, ls;
      split2(val, hs, ls);
      outH[oidx] = hs;
      outL[oidx] = ls;
    } else if (n + 1 < 256) {
      int u = t - 256, m = u >> 6, k = u & 63;
      int XQN = ((n + 1) & 1) * 288;
      unsigned short hs, ls;
      split2(rk, hs, ls); xkHp[m * 72 + k] = hs; xkLp[m * 72 + k] = ls;
      split2(rq, hs, ls); xqHp[XQN + m * 72 + k] = hs; xqLp[XQN + m * 72 + k] = ls;
      xvL[u] = rv;
    }
    __syncthreads();  // B8 (end of step)
  }
}

// final (4096,64) @ (64,1) + b
__global__ __launch_bounds__(256) void fc3_kernel(const float* __restrict__ f2,
                                                  const float* __restrict__ w,
                                                  const float* __restrict__ bias,
                                                  float* __restrict__ o) {
  int m = blockIdx.x * 4 + (threadIdx.x >> 6);
  int lane = threadIdx.x & 63;
  float v = f2[m * 64 + lane] * w[lane];
  v = wsum(v);
  if (lane == 0) o[m] = v + bias[0];
}

// ---------------------------------------------------------------------------
extern "C" void kernel_launch(void* const* d_in, const int* in_sizes, int n_in,
                              void* d_out, int out_size, void* d_ws, size_t ws_size,
                              hipStream_t stream) {
  const float* x       = (const float*)d_in[0];
  const float* conv1_w = (const float*)d_in[1];
  const float* conv1_b = (const float*)d_in[2];
  const float* convs_w = (const float*)d_in[3];
  const float* convs_b = (const float*)d_in[4];
  const float* ln_w    = (const float*)d_in[5];
  const float* ln_b    = (const float*)d_in[6];
  const float* wq      = (const float*)d_in[7];
  const float* wk      = (const float*)d_in[8];
  const float* wv      = (const float*)d_in[9];
  const float* wo      = (const float*)d_in[10];
  const float* ttt_W1  = (const float*)d_in[11];
  const float* ttt_b1  = (const float*)d_in[12];
  const float* ttt_W2  = (const float*)d_in[13];
  const float* ttt_b2  = (const float*)d_in[14];
  const float* ttt_lnw = (const float*)d_in[15];
  const float* ttt_lnb = (const float*)d_in[16];
  const float* fc_w    = (const float*)d_in[17];
  const float* fc_b    = (const float*)d_in[18];
  const float* fc2_w   = (const float*)d_in[19];
  const float* fc2_b   = (const float*)d_in[20];
  const float* fc3_w   = (const float*)d_in[21];
  const float* fc3_b   = (const float*)d_in[22];

  unsigned short* U = (unsigned short*)d_ws;
  unsigned short* WH   = U;
  unsigned short* WL   = U + 2015232;
  unsigned short* cAH  = U + 4030464;
  unsigned short* cAL  = U + 5081088;
  unsigned short* cBH  = U + 6131712;
  unsigned short* cBL  = U + 7182336;
  unsigned short* tlnH = U + 8232960;
  unsigned short* tlnL = U + 9281536;
  unsigned short* toH  = U + 10330112;
  unsigned short* toL  = U + 11378688;
  float* F = (float*)d_ws;
  float* sum4 = F + 6213632;
  float* XQ   = sum4;
  float* tfull = sum4;
  float* XK   = F + 7262208;
  float* XV   = F + 8310784;
  unsigned short* f1H = (unsigned short*)XK;
  unsigned short* f1L = (unsigned short*)XV;
  float* f2 = (float*)toH;
  unsigned short* h2H = cAH;
  unsigned short* h2L = cAL;

  const int W_WT1 = 0, W_WT = 16384, W_QKVO = 1589248, W_FC = 1851392, W_FC2 = 1982464;

  dim3 blk(256);

  zero_halo_pl<<<32, blk, 0, stream>>>(cAH, cAL, cBH, cBL);
  prep_all<<<7872, blk, 0, stream>>>(conv1_w, convs_w, wq, wk, wv, wo, fc_w,
                                     fc2_w, WH, WL);

  gemm_mf<1, 0, 1, 1, 1, 0><<<dim3(128, 4), blk, 0, stream>>>(
      nullptr, nullptr, x, WH + W_WT1, WL + W_WT1, conv1_b, nullptr, nullptr,
      nullptr, cAH, cAL, nullptr, 256, 64);

  for (int i = 0; i < 8; ++i) {
    const unsigned short* iH = (i % 2 == 0) ? cAH : cBH;
    const unsigned short* iL = (i % 2 == 0) ? cAL : cBL;
    unsigned short* oH = (i % 2 == 0) ? cBH : cAH;
    unsigned short* oL = (i % 2 == 0) ? cBL : cAL;
    const unsigned short* bH = WH + W_WT + i * 196608;
    const unsigned short* bL = WL + W_WT + i * 196608;
    const float* bp = convs_b + i * 256;
    if (i == 1)
      gemm_mf<0, 1, 1, 1, 1, 1><<<dim3(128, 4), blk, 0, stream>>>(
          iH, iL, nullptr, bH, bL, bp, nullptr, nullptr, nullptr, oH, oL, sum4,
          256, 768);
    else if (i == 3 || i == 5 || i == 7)
      gemm_mf<0, 1, 1, 1, 1, 2><<<dim3(128, 4), blk, 0, stream>>>(
          iH, iL, nullptr, bH, bL, bp, nullptr, nullptr, nullptr, oH, oL, sum4,
          256, 768);
    else
      gemm_mf<0, 1, 1, 1, 1, 0><<<dim3(128, 4), blk, 0, stream>>>(
          iH, iL, nullptr, bH, bL, bp, nullptr, nullptr, nullptr, oH, oL,
          nullptr, 256, 768);
  }

  ln_pl<<<1024, blk, 0, stream>>>(sum4, tlnH, tlnL, ln_w, ln_b, 1e-5f);

  gemm_mf<0, 0, 0, 0, 2, 0><<<dim3(128, 4), blk, 0, stream>>>(
      tlnH, tlnL, nullptr, WH + W_QKVO + 0 * 65536, WL + W_QKVO + 0 * 65536,
      nullptr, nullptr, nullptr, XQ, nullptr, nullptr, nullptr, 256, 256);
  gemm_mf<0, 0, 0, 0, 2, 0><<<dim3(128, 4), blk, 0, stream>>>(
      tlnH, tlnL, nullptr, WH + W_QKVO + 1 * 65536, WL + W_QKVO + 1 * 65536,
      nullptr, nullptr, nullptr, XK, nullptr, nullptr, nullptr, 256, 256);
  gemm_mf<0, 0, 0, 0, 2, 0><<<dim3(128, 4), blk, 0, stream>>>(
      tlnH, tlnL, nullptr, WH + W_QKVO + 2 * 65536, WL + W_QKVO + 2 * 65536,
      nullptr, nullptr, nullptr, XV, nullptr, nullptr, nullptr, 256, 256);

  // TTT scan: 16 chains, 512 threads, 163456 B dynamic LDS
  const int TTT_LDS = 163456;
  (void)hipFuncSetAttribute((const void*)ttt_mfma,
                            hipFuncAttributeMaxDynamicSharedMemorySize, TTT_LDS);
  ttt_mfma<<<16, dim3(512), TTT_LDS, stream>>>(XQ, XK, XV, ttt_W1, ttt_b1,
                                               ttt_W2, ttt_b2, ttt_lnw, ttt_lnb,
                                               toH, toL);

  gemm_mf<0, 0, 0, 0, 4, 0><<<dim3(128, 4), blk, 0, stream>>>(
      toH, toL, nullptr, WH + W_QKVO + 3 * 65536, WL + W_QKVO + 3 * 65536,
      nullptr, tlnH, tlnL, tfull, nullptr, nullptr, nullptr, 256, 256);

  ln_pl<<<1024, blk, 0, stream>>>(tfull, h2H, h2L, ln_w, ln_b, 1e-5f);

  gemm_mf<0, 0, 1, 0, 3, 0><<<dim3(128, 8), blk, 0, stream>>>(
      h2H, h2L, nullptr, WH + W_FC, WL + W_FC, fc_b, nullptr, nullptr, nullptr,
      f1H, f1L, nullptr, 512, 256);
  gemm_mf<0, 0, 1, 0, 0, 0><<<dim3(128, 1), blk, 0, stream>>>(
      f1H, f1L, nullptr, WH + W_FC2, WL + W_FC2, fc2_b, nullptr, nullptr, f2,
      nullptr, nullptr, nullptr, 64, 512);
  fc3_kernel<<<1024, blk, 0, stream>>>(f2, fc3_w, fc3_b, (float*)d_out);
}